// Round 1
// 1198.000 us; speedup vs baseline: 1.1180x; 1.1180x over previous
//
#include <hip/hip_runtime.h>

typedef _Float16 f16;
typedef _Float16 f16x2 __attribute__((ext_vector_type(2)));
typedef _Float16 f16x4 __attribute__((ext_vector_type(4)));
typedef _Float16 f16x8 __attribute__((ext_vector_type(8)));
typedef float f32x4 __attribute__((ext_vector_type(4)));

#define NB 256
#define NT 1024
#define ND 256
#define NU 128
#define NSIG 20
#define N3U 384
#define BT (NB * NT)
#define CH 16              // timesteps per LDS chunk
#define NCHUNK (NT / CH)

// xproj GEMM tile
#define BM 128
#define BN 128
#define BK 32
#define LDK 40             // padded LDS leading dim (f16): 2-way bank alias only

static __device__ __forceinline__ float sigmoid_fast(float x) {
    return __builtin_amdgcn_rcpf(1.f + __expf(-x));
}
static __device__ __forceinline__ float tanh_fast(float x) {
    return 1.f - 2.f * __builtin_amdgcn_rcpf(__expf(2.f * x) + 1.f);
}

// ---------------------------------------------------------------------------
// Kernel 1: x_proj = inputs @ input_kernel   [BT,256] @ [256,384] -> f16 [BT,384]
// R1: 128x128 tile, BK=32, 4 waves x (4x4 16x16 sub-tiles). Vectorized A
// staging (4x float4 -> cvt f16 -> 2x ds_write_b128). Fragment layout is the
// exact mm/q mapping of the previous verified 64x64 kernel.
// ---------------------------------------------------------------------------
__global__ __launch_bounds__(256) void xproj_gemm(
    const float* __restrict__ A,   // [BT, 256]
    const float* __restrict__ Wk,  // [256, 384]
    f16* __restrict__ out)         // [BT, 384]
{
    const int n0 = blockIdx.x * BN;
    const int m0 = blockIdx.y * BM;
    const int tid = threadIdx.x;
    const int lane = tid & 63;
    const int w = tid >> 6;
    const int mm = lane & 15;
    const int q = lane >> 4;
    const int wr = w >> 1;         // wave row (0..1) -> 64 rows
    const int wc = w & 1;          // wave col (0..1) -> 64 cols

    __shared__ __align__(16) f16 sA[BM * LDK];   // 10 KB, [row][k]
    __shared__ __align__(16) f16 sB[BN * LDK];   // 10 KB, [col][k]

    f32x4 acc[4][4];
    #pragma unroll
    for (int i = 0; i < 4; ++i)
        #pragma unroll
        for (int j = 0; j < 4; ++j)
            acc[i][j] = (f32x4){0.f, 0.f, 0.f, 0.f};

    const int ar = tid >> 1;           // A row 0..127
    const int ac = (tid & 1) * 16;     // A k-offset 0/16
    const int bn = tid >> 1;           // B col 0..127
    const int bk = (tid & 1) * 16;     // B k-offset 0/16

    for (int kt = 0; kt < ND; kt += BK) {
        // ---- A: 16 fp32 -> 16 f16 per thread (coalesced 64B/lane)
        const float* ap = A + (size_t)(m0 + ar) * ND + kt + ac;
        const float4 a0 = *(const float4*)(ap + 0);
        const float4 a1 = *(const float4*)(ap + 4);
        const float4 a2 = *(const float4*)(ap + 8);
        const float4 a3 = *(const float4*)(ap + 12);

        // ---- B: 16 scalar fp32 (coalesced across bn, L2-hot: Wk is 384 KB)
        f16x8 bv0, bv1;
        #pragma unroll
        for (int i = 0; i < 8; ++i)
            bv0[i] = (f16)Wk[(size_t)(kt + bk + i) * N3U + n0 + bn];
        #pragma unroll
        for (int i = 0; i < 8; ++i)
            bv1[i] = (f16)Wk[(size_t)(kt + bk + 8 + i) * N3U + n0 + bn];

        f16x8 av0, av1;
        av0[0]=(f16)a0.x; av0[1]=(f16)a0.y; av0[2]=(f16)a0.z; av0[3]=(f16)a0.w;
        av0[4]=(f16)a1.x; av0[5]=(f16)a1.y; av0[6]=(f16)a1.z; av0[7]=(f16)a1.w;
        av1[0]=(f16)a2.x; av1[1]=(f16)a2.y; av1[2]=(f16)a2.z; av1[3]=(f16)a2.w;
        av1[4]=(f16)a3.x; av1[5]=(f16)a3.y; av1[6]=(f16)a3.z; av1[7]=(f16)a3.w;

        *(f16x8*)(sA + ar * LDK + ac)     = av0;
        *(f16x8*)(sA + ar * LDK + ac + 8) = av1;
        *(f16x8*)(sB + bn * LDK + bk)     = bv0;
        *(f16x8*)(sB + bn * LDK + bk + 8) = bv1;

        __syncthreads();

        f16x8 afrag[4], bfrag[4];
        #pragma unroll
        for (int mi = 0; mi < 4; ++mi)
            afrag[mi] = *(const f16x8*)(sA + (wr * 64 + mi * 16 + mm) * LDK + q * 8);
        #pragma unroll
        for (int ni = 0; ni < 4; ++ni)
            bfrag[ni] = *(const f16x8*)(sB + (wc * 64 + ni * 16 + mm) * LDK + q * 8);

        #pragma unroll
        for (int mi = 0; mi < 4; ++mi)
            #pragma unroll
            for (int ni = 0; ni < 4; ++ni)
                acc[mi][ni] = __builtin_amdgcn_mfma_f32_16x16x32_f16(
                    afrag[mi], bfrag[ni], acc[mi][ni], 0, 0, 0);

        __syncthreads();
    }

    #pragma unroll
    for (int mi = 0; mi < 4; ++mi) {
        #pragma unroll
        for (int ni = 0; ni < 4; ++ni) {
            #pragma unroll
            for (int r = 0; r < 4; ++r) {
                const int row = m0 + wr * 64 + mi * 16 + q * 4 + r;
                const int col = n0 + wc * 64 + ni * 16 + mm;
                out[(size_t)row * N3U + col] = (f16)acc[mi][ni][r];
            }
        }
    }
}

// ---------------------------------------------------------------------------
// Kernel 2: f = sigmoid(signatures @ forget_kernel + b_f) -> f16 [BT,128]
// R1: 8 bt-rows per block (grid 32768 not 131072), Wf staged in LDS,
// 4 outputs/thread, float4 weight reads, 8B vector store.
// Accumulation order identical to R0 (bias first, s = 0..19).
// ---------------------------------------------------------------------------
__global__ __launch_bounds__(256) void fgate_kernel(
    const float* __restrict__ sig,
    const float* __restrict__ Wf,
    const float* __restrict__ bias,
    f16* __restrict__ fout)
{
    __shared__ float sWf[NSIG * NU];   // 10 KB
    __shared__ float sSig[8 * NSIG];   // 640 B
    const int tid = threadIdx.x;
    const int bt0 = blockIdx.x * 8;

    for (int i = tid; i < NSIG * NU; i += 256)
        sWf[i] = Wf[i];
    if (tid < 8 * NSIG)
        sSig[tid] = sig[(size_t)bt0 * NSIG + tid];
    __syncthreads();

    const int r = tid >> 5;            // local bt row 0..7
    const int u0 = (tid & 31) * 4;     // u 0..124

    float a0 = bias[NU + u0 + 0];
    float a1 = bias[NU + u0 + 1];
    float a2 = bias[NU + u0 + 2];
    float a3 = bias[NU + u0 + 3];
    #pragma unroll
    for (int s = 0; s < NSIG; ++s) {
        const float sv = sSig[r * NSIG + s];
        const float4 wv = *(const float4*)(&sWf[s * NU + u0]);
        a0 += sv * wv.x; a1 += sv * wv.y; a2 += sv * wv.z; a3 += sv * wv.w;
    }
    f16x4 o;
    o[0] = (f16)sigmoid_fast(a0);
    o[1] = (f16)sigmoid_fast(a1);
    o[2] = (f16)sigmoid_fast(a2);
    o[3] = (f16)sigmoid_fast(a3);
    *(f16x4*)(&fout[(size_t)(bt0 + r) * NU + u0]) = o;
}

// ---------------------------------------------------------------------------
// Kernel 3: recurrence — UNCHANGED from the verified 650 us version.
// ---------------------------------------------------------------------------
__global__ __launch_bounds__(384, 2) void recur_kernel(
    const f16* __restrict__ xp,      // [BT, 384]
    const f16* __restrict__ fg,      // [BT, 128]
    const float* __restrict__ Wr,    // [128, 384]
    const float* __restrict__ bias,  // [512]
    float* __restrict__ out)         // [BT, 128]
{
    const int b = blockIdx.x;
    const int j = threadIdx.x;

    __shared__ __align__(16) f16 x_sh[2][CH * N3U];   // 2 x 12 KB
    __shared__ __align__(16) f16 f_sh[2][CH * NU];    // 2 x 4 KB
    __shared__ __align__(16) float o_sh[CH * NU];     // 8 KB
    __shared__ __align__(16) f16 h_sh[2][NU];         // double-buffered h
    __shared__ __align__(16) float gate_sh[N3U];

    // ---- preload W_r column j into VGPRs as 64 packed f16x2 (fully unrolled)
    f16x2 wr[64];
    #pragma unroll
    for (int k2 = 0; k2 < 64; ++k2) {
        const float w0 = Wr[(size_t)(2 * k2) * N3U + j];
        const float w1 = Wr[(size_t)(2 * k2 + 1) * N3U + j];
        f16x2 p; p[0] = (f16)w0; p[1] = (f16)w1;
        wr[k2] = p;
    }

    float bi = 0.f, bc = 0.f, bo = 0.f, cstate = 0.f;
    if (j < NU) {
        bi = bias[j];
        bc = bias[2 * NU + j];
        bo = bias[3 * NU + j];
        h_sh[0][j] = (f16)0.f;
    }

    // ---- stage chunk 0 into buffer 0
    {
        const uint4* xsrc = (const uint4*)(xp + ((size_t)b * NT) * N3U);
        uint4* xdst = (uint4*)x_sh[0];
        xdst[j] = xsrc[j];
        xdst[j + 384] = xsrc[j + 384];
        if (j < 256) {
            const uint4* fsrc = (const uint4*)(fg + ((size_t)b * NT) * NU);
            ((uint4*)f_sh[0])[j] = fsrc[j];
        }
    }
    __syncthreads();

    int p = 0;   // h_sh buffer in use
    for (int c = 0; c < NCHUNK; ++c) {
        const int bb = c & 1;

        // issue next chunk's global loads NOW (held in regs until chunk end)
        uint4 xs0, xs1, fs0;
        const bool have_next = (c + 1 < NCHUNK);
        if (have_next) {
            const uint4* xsrc = (const uint4*)(xp + ((size_t)b * NT + (size_t)(c + 1) * CH) * N3U);
            xs0 = xsrc[j];
            xs1 = xsrc[j + 384];
            if (j < 256) {
                const uint4* fsrc = (const uint4*)(fg + ((size_t)b * NT + (size_t)(c + 1) * CH) * NU);
                fs0 = fsrc[j];
            }
        }

        for (int t = 0; t < CH; ++t) {
            // gate_j = x_j + sum_k h[k] * Wr[k][j]   (4 independent chains)
            float g0 = (float)x_sh[bb][t * N3U + j], g1 = 0.f, g2 = 0.f, g3 = 0.f;
            const uint4* h4 = (const uint4*)h_sh[p];
            #pragma unroll
            for (int kk = 0; kk < 16; ++kk) {
                const uint4 hv = h4[kk];   // wave-uniform address -> broadcast
                g0 = __builtin_amdgcn_fdot2(__builtin_bit_cast(f16x2, hv.x), wr[kk * 4 + 0], g0, false);
                g1 = __builtin_amdgcn_fdot2(__builtin_bit_cast(f16x2, hv.y), wr[kk * 4 + 1], g1, false);
                g2 = __builtin_amdgcn_fdot2(__builtin_bit_cast(f16x2, hv.z), wr[kk * 4 + 2], g2, false);
                g3 = __builtin_amdgcn_fdot2(__builtin_bit_cast(f16x2, hv.w), wr[kk * 4 + 3], g3, false);
            }
            gate_sh[j] = (g0 + g1) + (g2 + g3);
            __syncthreads();   // gates ready

            if (j < NU) {
                const float gi = gate_sh[j] + bi;
                const float gc = gate_sh[j + NU] + bc;
                const float go = gate_sh[j + 2 * NU] + bo;
                const float it = sigmoid_fast(gi);
                const float chv = tanh_fast(gc);
                const float ot = sigmoid_fast(go);
                const float ft = (float)f_sh[bb][t * NU + j];
                cstate = ft * cstate + it * chv;
                const float h = ot * tanh_fast(cstate);
                o_sh[t * NU + j] = h;
                h_sh[p ^ 1][j] = (f16)h;   // write OTHER buffer: no read race
            }
            __syncthreads();
            p ^= 1;
        }

        // ---- flush out chunk (8 KB contiguous, coalesced)
        {
            uint4* dst = (uint4*)(out + ((size_t)b * NT + (size_t)c * CH) * NU);
            const uint4* src = (const uint4*)o_sh;
            if (j < 256) {
                dst[j] = src[j];
                dst[j + 256] = src[j + 256];
            }
        }

        // ---- commit prefetched chunk to the other LDS buffer
        if (have_next) {
            uint4* xdst = (uint4*)x_sh[bb ^ 1];
            xdst[j] = xs0;
            xdst[j + 384] = xs1;
            if (j < 256) ((uint4*)f_sh[bb ^ 1])[j] = fs0;
        }
        __syncthreads();   // chunk barrier: staging visible, o_sh reads drained
    }
}

// ---------------------------------------------------------------------------
extern "C" void kernel_launch(void* const* d_in, const int* in_sizes, int n_in,
                              void* d_out, int out_size, void* d_ws, size_t ws_size,
                              hipStream_t stream) {
    const float* inputs = (const float*)d_in[0];   // [256,1024,256]
    const float* sig    = (const float*)d_in[1];   // [256,1024,20]
    const float* Wk     = (const float*)d_in[2];   // [256,384]
    const float* Wr     = (const float*)d_in[3];   // [128,384]
    const float* Wf     = (const float*)d_in[4];   // [20,128]
    const float* bias   = (const float*)d_in[5];   // [512]
    float* out = (float*)d_out;                    // [256,1024,128]

    f16* xp = (f16*)d_ws;
    f16* fg = (f16*)((char*)d_ws + (size_t)BT * N3U * sizeof(f16));

    xproj_gemm<<<dim3(N3U / BN, BT / BM), 256, 0, stream>>>(inputs, Wk, xp);
    fgate_kernel<<<dim3(BT / 8), 256, 0, stream>>>(sig, Wf, bias, fg);
    recur_kernel<<<dim3(NB), 384, 0, stream>>>(xp, fg, Wr, bias, out);

    (void)in_sizes; (void)n_in; (void)out_size; (void)ws_size;
}